// Round 1
// baseline (533.946 us; speedup 1.0000x reference)
//
#include <hip/hip_runtime.h>
#include <hip/hip_bf16.h>

typedef unsigned short u16;
typedef unsigned int u32;
typedef __attribute__((ext_vector_type(8))) short bf16x8;
typedef __attribute__((ext_vector_type(4))) float f32x4;
typedef __attribute__((ext_vector_type(4))) int i32x4;

#define N_HEADS 9
#define T_SEQ 2048
#define BATCH 4
#define CDIM 576
#define ROWS (BATCH * T_SEQ) /* 8192 */
#define AT_KT 128

__device__ __forceinline__ u16 f2bf(float f) {
    u32 u = __float_as_uint(f);
    u32 r = u + 0x7FFFu + ((u >> 16) & 1u);
    return (u16)(r >> 16);
}
__device__ __forceinline__ float bf2f(u16 u) { return __uint_as_float(((u32)u) << 16); }

// ---------------- prep kernels ----------------

__global__ void prep_convert_x(const float* __restrict__ x, u16* __restrict__ xb) {
    int i = (blockIdx.x * 256 + threadIdx.x) * 4;
    float4 v = *(const float4*)&x[i];
    u32 lo = (u32)f2bf(v.x) | ((u32)f2bf(v.y) << 16);
    u32 hi = (u32)f2bf(v.z) | ((u32)f2bf(v.w) << 16);
    uint2 pk; pk.x = lo; pk.y = hi;
    *(uint2*)&xb[i] = pk;
}

// WcT[576][576]: n-major, bf16. cols 0..188 Wq_sub, 189..377 Wk, 378..566 Wv, 567..575 zero
// WoSubT[576][192]: WoSubT[n][k] = Wo[(k/21)*64 + k%21][n] for k<189 else 0
__global__ void prep_weights(const float* __restrict__ Wq, const float* __restrict__ Wk,
                             const float* __restrict__ Wv, const float* __restrict__ Wo,
                             u16* __restrict__ WcT, u16* __restrict__ WoSubT) {
    int idx = blockIdx.x * 256 + threadIdx.x;
    if (idx < 576 * 576) {
        int n = idx / 576, k = idx - n * 576;
        float v;
        if (n < 189)      v = Wq[(size_t)k * 576 + (n / 21) * 64 + (n % 21)];
        else if (n < 378) v = Wk[(size_t)k * 189 + (n - 189)];
        else if (n < 567) v = Wv[(size_t)k * 189 + (n - 378)];
        else              v = 0.f;
        WcT[(size_t)n * 576 + k] = f2bf(v);
    }
    if (idx < 576 * 192) {
        int n = idx / 192, k = idx - n * 192;
        float v = 0.f;
        if (k < 189) v = Wo[(size_t)((k / 21) * 64 + (k % 21)) * 576 + n];
        WoSubT[(size_t)n * 192 + k] = f2bf(v);
    }
}

__global__ void prep_trig(float* __restrict__ cosT, float* __restrict__ sinT) {
    int idx = blockIdx.x * 256 + threadIdx.x;
    if (idx >= T_SEQ * 21) return;
    int t = idx / 21, d = idx - t * 21;
    int i = (d < 11) ? d : d - 11;
    float e = (2.0f * (float)i) / 21.0f;
    float pw = (float)pow(10000.0, (double)e);
    float invf = 1.0f / pw;
    float ang = (float)t * invf;
    double a = (double)ang;
    cosT[idx] = (float)cos(a);
    sinT[idx] = (float)sin(a);
}

// ---------------- bf16 MFMA GEMM: C[M,N] = A[M,K] * BT[N,K]^T ----------------
// 64x64 tile per block, 4 waves, each wave: 16 rows x 64 cols via 4x mfma 16x16x32.

template <int OUTF32>
__global__ __launch_bounds__(256) void gemm_mfma(const u16* __restrict__ A, const u16* __restrict__ BT,
                                                 void* __restrict__ Cout, int K, int lda, int ldbt, int ldc) {
    __shared__ u16 As[64][32];
    __shared__ u16 Bs[64][32];
    const int tid = threadIdx.x;
    const int lane = tid & 63, w = tid >> 6;
    const int m0 = blockIdx.x * 64, n0 = blockIdx.y * 64;
    const int srow = tid >> 2, sslot = tid & 3;

    f32x4 zero = {0.f, 0.f, 0.f, 0.f};
    f32x4 acc[4] = {zero, zero, zero, zero};

    const int ar = w * 16 + (lane & 15);
    const int ks = lane >> 4;

    for (int k0 = 0; k0 < K; k0 += 32) {
        i32x4 av = *(const i32x4*)&A[(size_t)(m0 + srow) * lda + k0 + sslot * 8];
        i32x4 bv = *(const i32x4*)&BT[(size_t)(n0 + srow) * ldbt + k0 + sslot * 8];
        __syncthreads();
        *(i32x4*)&As[srow][(sslot ^ (srow & 3)) * 8] = av;
        *(i32x4*)&Bs[srow][(sslot ^ (srow & 3)) * 8] = bv;
        __syncthreads();
        bf16x8 a = *(const bf16x8*)&As[ar][(ks ^ (ar & 3)) * 8];
#pragma unroll
        for (int n = 0; n < 4; n++) {
            int br = n * 16 + (lane & 15);
            bf16x8 b = *(const bf16x8*)&Bs[br][(ks ^ (br & 3)) * 8];
            acc[n] = __builtin_amdgcn_mfma_f32_16x16x32_bf16(a, b, acc[n], 0, 0, 0);
        }
    }
#pragma unroll
    for (int n = 0; n < 4; n++) {
#pragma unroll
        for (int i = 0; i < 4; i++) {
            int row = m0 + w * 16 + (lane >> 4) * 4 + i;
            int col = n0 + n * 16 + (lane & 15);
            float v = acc[n][i];
            if (OUTF32) ((float*)Cout)[(size_t)row * ldc + col] = v;
            else        ((u16*)Cout)[(size_t)row * ldc + col] = f2bf(v);
        }
    }
}

// ---------------- scalar flash attention ----------------
// Block: 256 threads = 256 consecutive q rows of one (b,h). Shares K/V LDS tiles.
// qkv row layout: [Q(189) | K(189) | V(189)] bf16 (unroped). RoPE applied here.

__global__ __launch_bounds__(256) void attn_flash(const u16* __restrict__ qkv,
                                                  const float* __restrict__ cosT,
                                                  const float* __restrict__ sinT,
                                                  u16* __restrict__ Ybuf) {
    __shared__ float Ks[AT_KT][24];
    __shared__ float Vs[AT_KT][24];
    const int bh = blockIdx.y;
    const int b = bh / N_HEADS, h = bh % N_HEADS;
    const int r0 = blockIdx.x * 256;
    const int row = r0 + threadIdx.x;

    float q[21];
    {
        const u16* qrow = qkv + (size_t)(b * T_SEQ + row) * CDIM + h * 21;
        float qraw[21];
#pragma unroll
        for (int d = 0; d < 21; d++) qraw[d] = bf2f(qrow[d]);
        const float* cr = cosT + row * 21;
        const float* sr = sinT + row * 21;
        const float sc = 0.125f * 1.44269504088896340736f; // scale * log2(e)
#pragma unroll
        for (int d = 0; d < 21; d++) {
            float rot = (d < 11) ? -qraw[d + 10] : qraw[d - 11];
            q[d] = (qraw[d] * cr[d] + rot * sr[d]) * sc;
        }
    }

    float m = -3.0e38f, l = 0.f;
    float y[21];
#pragma unroll
    for (int d = 0; d < 21; d++) y[d] = 0.f;

    const int kend = r0 + 256; // all keys this block can need (max row = r0+255)
    for (int k0 = 0; k0 < kend; k0 += AT_KT) {
        __syncthreads();
        for (int i = threadIdx.x; i < AT_KT * 21; i += 256) {
            int kr = i / 21, d = i - kr * 21;
            int t = k0 + kr;
            const u16* krow = qkv + (size_t)(b * T_SEQ + t) * CDIM + 189 + h * 21;
            const u16* vrow = krow + 189;
            float kd = bf2f(krow[d]);
            int pd = (d < 11) ? d + 10 : d - 11;
            float kp = bf2f(krow[pd]);
            float rot = (d < 11) ? -kp : kp;
            Ks[kr][d] = kd * cosT[t * 21 + d] + rot * sinT[t * 21 + d];
            Vs[kr][d] = bf2f(vrow[d]);
        }
        __syncthreads();
        int klim = row - k0 + 1;
        if (klim > AT_KT) klim = AT_KT;
        for (int kk = 0; kk < AT_KT; kk += 8) {
            if (kk >= klim) break;
            float s[8];
#pragma unroll
            for (int j = 0; j < 8; j++) {
                float kv[24];
#pragma unroll
                for (int d4 = 0; d4 < 6; d4++) *(float4*)&kv[d4 * 4] = *(const float4*)&Ks[kk + j][d4 * 4];
                float acc = q[0] * kv[0];
#pragma unroll
                for (int d = 1; d < 21; d++) acc = fmaf(q[d], kv[d], acc);
                s[j] = (kk + j < klim) ? acc : -3.0e38f;
            }
            float cmax = s[0];
#pragma unroll
            for (int j = 1; j < 8; j++) cmax = fmaxf(cmax, s[j]);
            if (cmax > m) {
                float alpha = exp2f(m - cmax);
                l *= alpha;
#pragma unroll
                for (int d = 0; d < 21; d++) y[d] *= alpha;
                m = cmax;
            }
            float p[8], ps = 0.f;
#pragma unroll
            for (int j = 0; j < 8; j++) { p[j] = exp2f(s[j] - m); ps += p[j]; }
            l += ps;
#pragma unroll
            for (int j = 0; j < 8; j++) {
                float vv[24];
#pragma unroll
                for (int d4 = 0; d4 < 6; d4++) *(float4*)&vv[d4 * 4] = *(const float4*)&Vs[kk + j][d4 * 4];
#pragma unroll
                for (int d = 0; d < 21; d++) y[d] = fmaf(p[j], vv[d], y[d]);
            }
        }
    }

    float inv = 1.0f / l;
    u16* yr = Ybuf + (size_t)(b * T_SEQ + row) * 192 + h * 21;
#pragma unroll
    for (int d = 0; d < 21; d++) yr[d] = f2bf(y[d] * inv);
    if (h == N_HEADS - 1) { yr[21] = 0; yr[22] = 0; yr[23] = 0; } // zero pad cols 189..191
}

// ---------------- launch ----------------

extern "C" void kernel_launch(void* const* d_in, const int* in_sizes, int n_in,
                              void* d_out, int out_size, void* d_ws, size_t ws_size,
                              hipStream_t stream) {
    const float* x  = (const float*)d_in[0];
    const float* Wq = (const float*)d_in[1];
    const float* Wk = (const float*)d_in[2];
    const float* Wv = (const float*)d_in[3];
    const float* Wo = (const float*)d_in[4];
    float* out = (float*)d_out;

    char* p = (char*)d_ws;
    auto alloc = [&](size_t bytes) { char* r = p; p += (bytes + 255) & ~(size_t)255; return r; };
    u16*   xb     = (u16*)alloc((size_t)ROWS * CDIM * 2);
    u16*   qkv    = (u16*)alloc((size_t)ROWS * CDIM * 2);
    u16*   WcT    = (u16*)alloc((size_t)576 * 576 * 2);
    u16*   WoSubT = (u16*)alloc((size_t)576 * 192 * 2);
    float* cosT   = (float*)alloc((size_t)T_SEQ * 21 * 4);
    float* sinT   = (float*)alloc((size_t)T_SEQ * 21 * 4);
    u16*   Ybuf   = (u16*)alloc((size_t)ROWS * 192 * 2);

    prep_convert_x<<<dim3(ROWS * CDIM / 4 / 256), dim3(256), 0, stream>>>(x, xb);
    prep_weights<<<dim3((576 * 576 + 255) / 256), dim3(256), 0, stream>>>(Wq, Wk, Wv, Wo, WcT, WoSubT);
    prep_trig<<<dim3((T_SEQ * 21 + 255) / 256), dim3(256), 0, stream>>>(cosT, sinT);

    // QKV projection: [8192,576] x [576 -> 576(567 valid)]
    gemm_mfma<0><<<dim3(ROWS / 64, 576 / 64), dim3(256), 0, stream>>>(xb, WcT, (void*)qkv, 576, 576, 576, 576);

    // flash attention, 36 (b,h) pairs x 8 row-blocks
    attn_flash<<<dim3(T_SEQ / 256, BATCH * N_HEADS), dim3(256), 0, stream>>>(qkv, cosT, sinT, Ybuf);

    // output GEMM: [8192,192] x [192,576]
    gemm_mfma<1><<<dim3(ROWS / 64, 576 / 64), dim3(256), 0, stream>>>(Ybuf, WoSubT, (void*)out, 192, 192, 192, 576);
}

// Round 4
// 159.589 us; speedup vs baseline: 3.3458x; 3.3458x over previous
//
#include <hip/hip_runtime.h>
#include <hip/hip_bf16.h>

typedef unsigned short u16;
typedef unsigned int u32;
typedef __attribute__((ext_vector_type(8))) short bf16x8;
typedef __attribute__((ext_vector_type(4))) float f32x4;
typedef __attribute__((ext_vector_type(4))) int i32x4;

#define N_HEADS 9
#define T_SEQ 2048
#define BATCH 4
#define CDIM 576
#define ROWS (BATCH * T_SEQ) /* 8192 */
#define NBH (BATCH * N_HEADS) /* 36 */

__device__ __forceinline__ u16 f2bf(float f) {
    u32 u = __float_as_uint(f);
    u32 r = u + 0x7FFFu + ((u >> 16) & 1u);
    return (u16)(r >> 16);
}
__device__ __forceinline__ float bf2f(u16 u) { return __uint_as_float(((u32)u) << 16); }

// ---------------- prep kernels ----------------

__global__ void prep_convert_x(const float* __restrict__ x, u16* __restrict__ xb) {
    int i = (blockIdx.x * 256 + threadIdx.x) * 4;
    float4 v = *(const float4*)&x[i];
    u32 lo = (u32)f2bf(v.x) | ((u32)f2bf(v.y) << 16);
    u32 hi = (u32)f2bf(v.z) | ((u32)f2bf(v.w) << 16);
    uint2 pk; pk.x = lo; pk.y = hi;
    *(uint2*)&xb[i] = pk;
}

// WcT[576][576]: n-major bf16. cols 0..188 Wq_sub, 189..377 Wk, 378..566 Wv, 567..575 zero
// WoSubT[576][192]: WoSubT[n][k] = Wo[(k/21)*64 + k%21][n] for k<189 else 0
__global__ void prep_weights(const float* __restrict__ Wq, const float* __restrict__ Wk,
                             const float* __restrict__ Wv, const float* __restrict__ Wo,
                             u16* __restrict__ WcT, u16* __restrict__ WoSubT) {
    int idx = blockIdx.x * 256 + threadIdx.x;
    if (idx < 576 * 576) {
        int n = idx / 576, k = idx - n * 576;
        float v;
        if (n < 189)      v = Wq[(size_t)k * 576 + (n / 21) * 64 + (n % 21)];
        else if (n < 378) v = Wk[(size_t)k * 189 + (n - 189)];
        else if (n < 567) v = Wv[(size_t)k * 189 + (n - 378)];
        else              v = 0.f;
        WcT[(size_t)n * 576 + k] = f2bf(v);
    }
    if (idx < 576 * 192) {
        int n = idx / 192, k = idx - n * 192;
        float v = 0.f;
        if (k < 189) v = Wo[(size_t)((k / 21) * 64 + (k % 21)) * 576 + n];
        WoSubT[(size_t)n * 192 + k] = f2bf(v);
    }
}

__global__ void prep_trig(float* __restrict__ cosT, float* __restrict__ sinT) {
    int idx = blockIdx.x * 256 + threadIdx.x;
    if (idx >= T_SEQ * 21) return;
    int t = idx / 21, d = idx - t * 21;
    int i = (d < 11) ? d : d - 11;
    float e = (2.0f * (float)i) / 21.0f;
    float pw = (float)pow(10000.0, (double)e);
    float invf = 1.0f / pw;
    float ang = (float)t * invf;
    double a = (double)ang;
    cosT[idx] = (float)cos(a);
    sinT[idx] = (float)sin(a);
}

// ---------------- bf16 MFMA GEMM: C[M,N] = A[M,K] * BT[N,K]^T ----------------

template <int OUTF32>
__global__ __launch_bounds__(256) void gemm_mfma(const u16* __restrict__ A, const u16* __restrict__ BT,
                                                 void* __restrict__ Cout, int K, int lda, int ldbt, int ldc) {
    __shared__ u16 As[64][32];
    __shared__ u16 Bs[64][32];
    const int tid = threadIdx.x;
    const int lane = tid & 63, w = tid >> 6;
    const int m0 = blockIdx.x * 64, n0 = blockIdx.y * 64;
    const int srow = tid >> 2, sslot = tid & 3;

    f32x4 zero = {0.f, 0.f, 0.f, 0.f};
    f32x4 acc[4] = {zero, zero, zero, zero};

    const int ar = w * 16 + (lane & 15);
    const int ks = lane >> 4;

    for (int k0 = 0; k0 < K; k0 += 32) {
        i32x4 av = *(const i32x4*)&A[(size_t)(m0 + srow) * lda + k0 + sslot * 8];
        i32x4 bv = *(const i32x4*)&BT[(size_t)(n0 + srow) * ldbt + k0 + sslot * 8];
        __syncthreads();
        *(i32x4*)&As[srow][(sslot ^ (srow & 3)) * 8] = av;
        *(i32x4*)&Bs[srow][(sslot ^ (srow & 3)) * 8] = bv;
        __syncthreads();
        bf16x8 a = *(const bf16x8*)&As[ar][(ks ^ (ar & 3)) * 8];
#pragma unroll
        for (int n = 0; n < 4; n++) {
            int br = n * 16 + (lane & 15);
            bf16x8 b = *(const bf16x8*)&Bs[br][(ks ^ (br & 3)) * 8];
            acc[n] = __builtin_amdgcn_mfma_f32_16x16x32_bf16(a, b, acc[n], 0, 0, 0);
        }
    }
#pragma unroll
    for (int n = 0; n < 4; n++) {
#pragma unroll
        for (int i = 0; i < 4; i++) {
            int row = m0 + w * 16 + (lane >> 4) * 4 + i;
            int col = n0 + n * 16 + (lane & 15);
            float v = acc[n][i];
            if (OUTF32) ((float*)Cout)[(size_t)row * ldc + col] = v;
            else        ((u16*)Cout)[(size_t)row * ldc + col] = f2bf(v);
        }
    }
}

// ---------------- repack: rope + pad to d=32, per-head layouts ----------------
// Qp[bh][t][32] (roped, scaled by 0.125*log2e), Kp[bh][t][32] (roped), Vp[bh][32][2048] (d-major, col31 = 1.0)

__global__ __launch_bounds__(256) void repack_qk(const u16* __restrict__ qkv,
                                                 const float* __restrict__ cosT,
                                                 const float* __restrict__ sinT,
                                                 u16* __restrict__ Qp, u16* __restrict__ Kp) {
    int gid = blockIdx.x * 256 + threadIdx.x; // 36*2048*4
    int c = gid & 3;
    int t = (gid >> 2) & 2047;
    int bh = gid >> 13;
    int b = bh / N_HEADS, h = bh - b * N_HEADS;
    const u16* qrow = qkv + (size_t)(b * T_SEQ + t) * CDIM + h * 21;
    const u16* krow = qrow + 189;
    const float* cr = cosT + t * 21;
    const float* sr = sinT + t * 21;
    u32 wq[4] = {0, 0, 0, 0}, wk[4] = {0, 0, 0, 0};
    const float sc = 0.18033688011112042f; // 0.125 * log2(e)
#pragma unroll
    for (int j = 0; j < 8; j++) {
        int d = c * 8 + j;
        float vq = 0.f, vk = 0.f;
        if (d < 21) {
            int pd = (d < 11) ? d + 10 : d - 11;
            float cc = cr[d], ss = sr[d];
            float qv = bf2f(qrow[d]), qp = bf2f(qrow[pd]);
            float kv = bf2f(krow[d]), kp = bf2f(krow[pd]);
            float rq = (d < 11) ? -qp : qp;
            float rk = (d < 11) ? -kp : kp;
            vq = (qv * cc + rq * ss) * sc;
            vk = kv * cc + rk * ss;
        }
        wq[j >> 1] |= (u32)f2bf(vq) << ((j & 1) * 16);
        wk[j >> 1] |= (u32)f2bf(vk) << ((j & 1) * 16);
    }
    size_t obase = ((size_t)bh * T_SEQ + t) * 32 + c * 8;
    i32x4 q4; q4[0] = (int)wq[0]; q4[1] = (int)wq[1]; q4[2] = (int)wq[2]; q4[3] = (int)wq[3];
    i32x4 k4; k4[0] = (int)wk[0]; k4[1] = (int)wk[1]; k4[2] = (int)wk[2]; k4[3] = (int)wk[3];
    *(i32x4*)&Qp[obase] = q4;
    *(i32x4*)&Kp[obase] = k4;
}

__global__ __launch_bounds__(256) void repack_v(const u16* __restrict__ qkv, u16* __restrict__ Vp) {
    int gid = blockIdx.x * 256 + threadIdx.x; // 36*32*256
    int tc = gid & 255;
    int d = (gid >> 8) & 31;
    int bh = gid >> 13;
    int b = bh / N_HEADS, h = bh - b * N_HEADS;
    u32 wv[4];
#pragma unroll
    for (int jj = 0; jj < 4; jj++) {
        u16 lo = 0, hi = 0;
#pragma unroll
        for (int e = 0; e < 2; e++) {
            int t = tc * 8 + jj * 2 + e;
            u16 val;
            if (d < 21)      val = qkv[(size_t)(b * T_SEQ + t) * CDIM + 378 + h * 21 + d];
            else if (d == 31) val = 0x3F80; // 1.0 bf16 (denominator column)
            else             val = 0;
            if (e == 0) lo = val; else hi = val;
        }
        wv[jj] = (u32)lo | ((u32)hi << 16);
    }
    i32x4 v4; v4[0] = (int)wv[0]; v4[1] = (int)wv[1]; v4[2] = (int)wv[2]; v4[3] = (int)wv[3];
    *(i32x4*)&Vp[(size_t)bh * 32 * T_SEQ + (size_t)d * T_SEQ + tc * 8] = v4;
}

// ---------------- MFMA flash attention ----------------
// block = (qtile 64 rows) x (bh). 4 waves, wave w owns q rows q0+w*16..+15.
// S^T = mfma(K, Q): lane col = q (lane&15), rows = keys. l via V ones-column (d=31).

__global__ __launch_bounds__(256) void attn_mfma(const u16* __restrict__ Qp,
                                                 const u16* __restrict__ Kp,
                                                 const u16* __restrict__ Vp,
                                                 u16* __restrict__ Ybuf) {
    __shared__ u16 Ks[64][40];     // key-major, padded (80B rows, 16B aligned)
    __shared__ u16 Vt[32][72];     // d-major, padded (144B rows)
    __shared__ u16 Pt[4][16][72];  // per-wave P^T: [q][key]
    const int tid = threadIdx.x;
    const int lane = tid & 63, w = tid >> 6;
    const int bh = blockIdx.y;
    const int b = bh / N_HEADS, h = bh - b * N_HEADS;
    const int q0 = blockIdx.x * 64;
    const int k15 = lane & 15, g = lane >> 4;

    // Q B-fragment (held in regs whole kernel): B[n=q][k=d]
    bf16x8 qf = *(const bf16x8*)&Qp[(((size_t)bh << 11) + q0 + w * 16 + k15) * 32 + g * 8];

    f32x4 y0 = {0.f, 0.f, 0.f, 0.f}, y1 = {0.f, 0.f, 0.f, 0.f};
    float m = -1e9f;

    const int kst = tid >> 2, ksc = tid & 3;  // K staging: (key, 16B chunk)
    const int vsd = tid >> 3, vsc = tid & 7;  // V staging: (d, 16B chunk)

    const int qloc = w * 16 + k15;            // wave-local causal row index within the 64-q tile

    for (int k0 = 0; k0 <= q0; k0 += 64) {
        __syncthreads();
        *(i32x4*)&Ks[kst][ksc * 8] =
            *(const i32x4*)&Kp[(((size_t)bh << 11) + k0 + kst) * 32 + ksc * 8];
        *(i32x4*)&Vt[vsd][vsc * 8] =
            *(const i32x4*)&Vp[((size_t)bh * 32 + vsd) * T_SEQ + k0 + vsc * 8];
        __syncthreads();

        // QK^T (swapped): S^T frag f: rows = keys f*16+g*4+i, col = q = k15
        f32x4 s[4];
#pragma unroll
        for (int f = 0; f < 4; f++) {
            bf16x8 kf = *(const bf16x8*)&Ks[f * 16 + k15][g * 8];
            f32x4 z = {0.f, 0.f, 0.f, 0.f};
            s[f] = __builtin_amdgcn_mfma_f32_16x16x32_bf16(kf, qf, z, 0, 0, 0);
        }
        if (k0 == q0) { // diagonal tile: mask key_local > w*16 + q_local
#pragma unroll
            for (int f = 0; f < 4; f++)
#pragma unroll
                for (int i = 0; i < 4; i++)
                    if (f * 16 + g * 4 + i > qloc) s[f][i] = -1e9f;
        }
        // row (=q) max: in-lane 16 + butterfly over g
        float t0 = fmaxf(fmaxf(s[0][0], s[0][1]), fmaxf(s[0][2], s[0][3]));
        float t1 = fmaxf(fmaxf(s[1][0], s[1][1]), fmaxf(s[1][2], s[1][3]));
        float t2 = fmaxf(fmaxf(s[2][0], s[2][1]), fmaxf(s[2][2], s[2][3]));
        float t3 = fmaxf(fmaxf(s[3][0], s[3][1]), fmaxf(s[3][2], s[3][3]));
        float tmax = fmaxf(fmaxf(t0, t1), fmaxf(t2, t3));
        tmax = fmaxf(tmax, __shfl_xor(tmax, 16));
        tmax = fmaxf(tmax, __shfl_xor(tmax, 32));
        float mnew = fmaxf(m, tmax);
        float alpha = exp2f(m - mnew);
        m = mnew;

        // P = exp2(S - m), pack bf16, write P^T column (b64)
#pragma unroll
        for (int f = 0; f < 4; f++) {
            u32 lo = (u32)f2bf(exp2f(s[f][0] - m)) | ((u32)f2bf(exp2f(s[f][1] - m)) << 16);
            u32 hi = (u32)f2bf(exp2f(s[f][2] - m)) | ((u32)f2bf(exp2f(s[f][3] - m)) << 16);
            uint2 pk; pk.x = lo; pk.y = hi;
            *(uint2*)&Pt[w][k15][f * 16 + g * 4] = pk;
        }
        asm volatile("" ::: "memory"); // keep write->read order (same wave, in-order LDS)

        // rescale y accumulators (rows g*4+i) by that row's alpha
#pragma unroll
        for (int i = 0; i < 4; i++) {
            float al = __shfl(alpha, (lane & 48) + g * 4 + i);
            y0[i] *= al;
            y1[i] *= al;
        }

        // PV: A[m=q][k=key] from Pt, B[n=d][k=key] from Vt
#pragma unroll
        for (int kh = 0; kh < 2; kh++) {
            bf16x8 pa = *(const bf16x8*)&Pt[w][k15][kh * 32 + g * 8];
            bf16x8 v0 = *(const bf16x8*)&Vt[k15][kh * 32 + g * 8];
            bf16x8 v1 = *(const bf16x8*)&Vt[16 + k15][kh * 32 + g * 8];
            y0 = __builtin_amdgcn_mfma_f32_16x16x32_bf16(pa, v0, y0, 0, 0, 0);
            y1 = __builtin_amdgcn_mfma_f32_16x16x32_bf16(pa, v1, y1, 0, 0, 0);
        }
    }

    // normalize by l (= y1 col 15, i.e. d=31 ones-column) and write d<21
#pragma unroll
    for (int i = 0; i < 4; i++) {
        float li = __shfl(y1[i], (lane & 48) + 15);
        float inv = 1.0f / li;
        int rowY = b * T_SEQ + q0 + w * 16 + g * 4 + i;
        u16* yr = &Ybuf[(size_t)rowY * 192 + h * 21];
        yr[k15] = f2bf(y0[i] * inv);                 // d = 0..15
        if (k15 < 5) yr[16 + k15] = f2bf(y1[i] * inv); // d = 16..20
    }
}

// ---------------- launch ----------------

extern "C" void kernel_launch(void* const* d_in, const int* in_sizes, int n_in,
                              void* d_out, int out_size, void* d_ws, size_t ws_size,
                              hipStream_t stream) {
    const float* x  = (const float*)d_in[0];
    const float* Wq = (const float*)d_in[1];
    const float* Wk = (const float*)d_in[2];
    const float* Wv = (const float*)d_in[3];
    const float* Wo = (const float*)d_in[4];
    float* out = (float*)d_out;

    char* p = (char*)d_ws;
    auto alloc = [&](size_t bytes) { char* r = p; p += (bytes + 255) & ~(size_t)255; return r; };
    u16*   xb     = (u16*)alloc((size_t)ROWS * CDIM * 2);   // reused: Qp | Kp after gemm1
    u16*   qkv    = (u16*)alloc((size_t)ROWS * CDIM * 2);
    u16*   WcT    = (u16*)alloc((size_t)576 * 576 * 2);
    u16*   WoSubT = (u16*)alloc((size_t)576 * 192 * 2);
    float* cosT   = (float*)alloc((size_t)T_SEQ * 21 * 4);
    float* sinT   = (float*)alloc((size_t)T_SEQ * 21 * 4);
    u16*   Vp     = (u16*)alloc((size_t)NBH * 32 * T_SEQ * 2);
    u16*   Ybuf   = (u16*)alloc((size_t)ROWS * 192 * 2);

    u16* Qp = xb;                                  // 4.71 MB (xb dead after gemm1)
    u16* Kp = xb + (size_t)NBH * T_SEQ * 32;       // second half of xb

    prep_convert_x<<<dim3(ROWS * CDIM / 4 / 256), dim3(256), 0, stream>>>(x, xb);
    prep_weights<<<dim3((576 * 576 + 255) / 256), dim3(256), 0, stream>>>(Wq, Wk, Wv, Wo, WcT, WoSubT);
    prep_trig<<<dim3((T_SEQ * 21 + 255) / 256), dim3(256), 0, stream>>>(cosT, sinT);

    // QKV projection: [8192,576] x [576,567(->576)]
    gemm_mfma<0><<<dim3(ROWS / 64, 576 / 64), dim3(256), 0, stream>>>(xb, WcT, (void*)qkv, 576, 576, 576, 576);

    // rope + repack (xb no longer read)
    repack_qk<<<dim3(NBH * T_SEQ * 4 / 256), dim3(256), 0, stream>>>(qkv, cosT, sinT, Qp, Kp);
    repack_v<<<dim3(NBH * 32 * 256 / 256), dim3(256), 0, stream>>>(qkv, Vp);

    // MFMA flash attention
    attn_mfma<<<dim3(T_SEQ / 64, NBH), dim3(256), 0, stream>>>(Qp, Kp, Vp, Ybuf);

    // output GEMM: [8192,192] x [192,576]
    gemm_mfma<1><<<dim3(ROWS / 64, 576 / 64), dim3(256), 0, stream>>>(Ybuf, WoSubT, (void*)out, 192, 192, 192, 576);
}